// Round 1
// baseline (267.280 us; speedup 1.0000x reference)
//
#include <hip/hip_runtime.h>
#include <hip/hip_bf16.h>

// GIN layer: out = relu(((1+eps)*x + segment_sum(x[src], dst)) @ W1 + b1) @ W2 + b2
// Restructured via linearity: y = x@W1 (bf16); h = relu((1+eps)*y[i] + sum_j y[j] + b1);
// out = h@W2 + b2. CSR build via global-atomic counting sort (padded counters).
// N=50000 nodes, E=1.6M edges, D=128.

#define N_NODES 50000
#define N_EDGES 1600000
#define D 128
#define DEGP 16          // counter padding: 16 u32 = 64 B per node (kills line serialization)

typedef __attribute__((ext_vector_type(8))) short short8;
typedef __attribute__((ext_vector_type(4))) float float4v;

__device__ inline unsigned short f2b(float f) {
    unsigned u = __builtin_bit_cast(unsigned, f);
    u = u + 0x7fffu + ((u >> 16) & 1u);  // RNE
    return (unsigned short)(u >> 16);
}
__device__ inline float b2f_lo(unsigned u) { return __builtin_bit_cast(float, u << 16); }
__device__ inline float b2f_hi(unsigned u) { return __builtin_bit_cast(float, u & 0xffff0000u); }

#define LPAD 136

// ---------------- y = bf16(x @ W1)  (f32 A staged+converted in LDS; no bias/relu) ------
// Also: block 0 detects int64-vs-int32 edge layout; all blocks zero the padded counters.
__global__ __launch_bounds__(256, 2) void k_gemmY(const float* __restrict__ x,
                                                  const float* __restrict__ Wg,
                                                  unsigned short* __restrict__ y,
                                                  const int* __restrict__ ei,
                                                  int* __restrict__ flag,
                                                  uint4* __restrict__ degz) {
    if (blockIdx.x == 0) {
        __shared__ int nz;
        if (threadIdx.x == 0) nz = 0;
        __syncthreads();
        if (ei[threadIdx.x * 2 + 1] != 0) atomicAdd(&nz, 1);
        __syncthreads();
        if (threadIdx.x == 0) *flag = (nz == 0) ? 1 : 0;  // 1 => int64 layout
    }
    {   // zero 50000*16 u32 = 200000 uint4 of padded degree counters
        int gid = blockIdx.x * 256 + threadIdx.x;           // 0..100095
        if (gid < 200000) degz[gid] = make_uint4(0u, 0u, 0u, 0u);
        int gid2 = gid + 100096;
        if (gid2 < 200000) degz[gid2] = make_uint4(0u, 0u, 0u, 0u);
    }

    __shared__ short Al[128 * LPAD];   // [row][k] bf16
    __shared__ short Wt[128 * LPAD];   // [n][k]   bf16 (transposed W)
    int t = threadIdx.x;
    int row0 = blockIdx.x * 128;

    const float4* X4 = (const float4*)x;
    #pragma unroll
    for (int i = 0; i < 16; ++i) {
        int idx = i * 256 + t;      // 0..4095
        int r = idx >> 5;           // 0..127
        int c = idx & 31;           // float4 within row
        float4 v = make_float4(0.f, 0.f, 0.f, 0.f);
        if (row0 + r < N_NODES) v = X4[(size_t)(row0 + r) * 32 + c];
        short4 o;
        o.x = (short)f2b(v.x); o.y = (short)f2b(v.y);
        o.z = (short)f2b(v.z); o.w = (short)f2b(v.w);
        *(short4*)&Al[r * LPAD + c * 4] = o;
    }
    const float4* W4 = (const float4*)Wg;
    #pragma unroll
    for (int i = 0; i < 16; ++i) {
        int idx = i * 256 + t;
        int k = idx >> 5;
        int n4 = idx & 31;
        float4 v = W4[k * 32 + n4];
        Wt[(n4 * 4 + 0) * LPAD + k] = (short)f2b(v.x);
        Wt[(n4 * 4 + 1) * LPAD + k] = (short)f2b(v.y);
        Wt[(n4 * 4 + 2) * LPAD + k] = (short)f2b(v.z);
        Wt[(n4 * 4 + 3) * LPAD + k] = (short)f2b(v.w);
    }
    __syncthreads();

    int wave = t >> 6;
    int lane = t & 63;
    int quad = lane >> 4;
    int l16 = lane & 15;
    int rowbase = wave * 32;

    float4v acc[2][8];
    #pragma unroll
    for (int mt = 0; mt < 2; ++mt)
        #pragma unroll
        for (int nt = 0; nt < 8; ++nt)
            acc[mt][nt] = (float4v){0.f, 0.f, 0.f, 0.f};

    #pragma unroll
    for (int kc = 0; kc < 4; ++kc) {
        int koff = kc * 32 + quad * 8;
        short8 a0 = *(const short8*)&Al[(rowbase + l16) * LPAD + koff];
        short8 a1 = *(const short8*)&Al[(rowbase + 16 + l16) * LPAD + koff];
        #pragma unroll
        for (int nt = 0; nt < 8; ++nt) {
            short8 bfr = *(const short8*)&Wt[(nt * 16 + l16) * LPAD + koff];
            acc[0][nt] = __builtin_amdgcn_mfma_f32_16x16x32_bf16(a0, bfr, acc[0][nt], 0, 0, 0);
            acc[1][nt] = __builtin_amdgcn_mfma_f32_16x16x32_bf16(a1, bfr, acc[1][nt], 0, 0, 0);
        }
    }

    #pragma unroll
    for (int mt = 0; mt < 2; ++mt) {
        int rloc = rowbase + mt * 16 + quad * 4;
        #pragma unroll
        for (int nt = 0; nt < 8; ++nt) {
            int col = nt * 16 + l16;
            #pragma unroll
            for (int r = 0; r < 4; ++r) {
                int grow = row0 + rloc + r;
                if (grow < N_NODES)
                    y[(size_t)grow * 128 + col] = f2b(acc[mt][nt][r]);
            }
        }
    }
}

// ---------------- count: deg[d]++ via global atomic; pack (rank<<16)|d per edge --------
__global__ __launch_bounds__(1024) void k_count(const int* __restrict__ ei,
                                                const int* __restrict__ flag,
                                                unsigned* __restrict__ degp,
                                                unsigned* __restrict__ pack) {
    int e = blockIdx.x * 1024 + threadIdx.x;
    if (e >= N_EDGES) return;
    int wide = *flag;
    long long di = (long long)N_EDGES + e;
    int d = wide ? ei[di * 2] : ei[di];
    unsigned p = 0xffffffffu;   // invalid marker (d<50000 => low16 never 0xffff)
    if ((unsigned)d < (unsigned)N_NODES) {
        unsigned r = atomicAdd(&degp[(size_t)d * DEGP], 1u);
        p = (r << 16) | (unsigned)d;
    }
    pack[e] = p;  // coalesced
}

// ---------------- scan A: per-block (512-node) exclusive scan of degrees --------------
__global__ __launch_bounds__(512) void k_scanA(const unsigned* __restrict__ degp,
                                               int* __restrict__ offsets,
                                               int* __restrict__ bsum) {
    __shared__ int tmp[512];
    int t = threadIdx.x;
    int d = blockIdx.x * 512 + t;
    int run = (d < N_NODES) ? (int)degp[(size_t)d * DEGP] : 0;
    tmp[t] = run;
    __syncthreads();
    for (int off = 1; off < 512; off <<= 1) {
        int u = (t >= off) ? tmp[t - off] : 0;
        __syncthreads();
        tmp[t] += u;
        __syncthreads();
    }
    if (d < N_NODES) offsets[d] = tmp[t] - run;
    if (t == 511) bsum[blockIdx.x] = tmp[511];
}

// ---------------- scan B: redundant scan of 98 block sums + add base ------------------
__global__ __launch_bounds__(512) void k_scan23(int* __restrict__ offsets,
                                                const int* __restrict__ bsum, int nb) {
    __shared__ int tmp[128];
    int t = threadIdx.x;
    if (t < 128) tmp[t] = (t < nb) ? bsum[t] : 0;
    __syncthreads();
    for (int off = 1; off < 128; off <<= 1) {
        int v = (t >= off && t < 128) ? tmp[t - off] : 0;
        __syncthreads();
        if (t < 128) tmp[t] += v;
        __syncthreads();
    }
    int base = (blockIdx.x == 0) ? 0 : tmp[blockIdx.x - 1];
    int gid = blockIdx.x * 512 + t;
    if (gid < N_NODES) offsets[gid] += base;
}

// ---------------- place: srcs[offsets[d] + rank] = s (no second atomic) ---------------
__global__ __launch_bounds__(1024) void k_place(const int* __restrict__ ei,
                                                const int* __restrict__ flag,
                                                const int* __restrict__ offsets,
                                                const unsigned* __restrict__ pack,
                                                int* __restrict__ srcs) {
    int e = blockIdx.x * 1024 + threadIdx.x;
    if (e >= N_EDGES) return;
    int wide = *flag;
    int s = wide ? ei[(long long)e * 2] : ei[e];
    unsigned p = pack[e];
    if (p != 0xffffffffu && (unsigned)s < (unsigned)N_NODES) {
        int d = (int)(p & 0xffffu);
        int r = (int)(p >> 16);
        srcs[offsets[d] + r] = s;
    }
}

// ---------------- gather over y, fused epilogue of layer 1 ----------------------------
// h[i] = bf16(relu((1+eps)*y[i] + sum_{j in N(i)} y[j] + b1))
// One wave per node (block = 4 nodes). Row = 32 lanes x uint2 (256 B); 2 neighbor
// groups x unroll 8 = 16 outstanding row loads per wave.
__global__ __launch_bounds__(256) void k_gather(const unsigned short* __restrict__ y,
                                                const int* __restrict__ srcs,
                                                const int* __restrict__ offsets,
                                                const unsigned* __restrict__ degp,
                                                const float* __restrict__ b1,
                                                unsigned short* __restrict__ h) {
    int node = blockIdx.x * 4 + (threadIdx.x >> 6);
    int lane = threadIdx.x & 63;
    int g = lane >> 5;    // neighbor group 0..1
    int u = lane & 31;    // uint2 index within row (32 x 8 B = 256 B)
    if (node >= N_NODES) return;
    int beg = offsets[node];
    int end = beg + (int)degp[(size_t)node * DEGP];
    const uint2* yr = (const uint2*)y;
    float a0 = 0.f, a1 = 0.f, a2 = 0.f, a3 = 0.f;
    int j = beg + g;
    for (; j + 14 < end; j += 16) {
        int ss[8];
        #pragma unroll
        for (int q = 0; q < 8; ++q) ss[q] = srcs[j + 2 * q];
        #pragma unroll
        for (int q = 0; q < 8; ++q) {
            uint2 A = yr[(size_t)ss[q] * 32 + u];
            a0 += b2f_lo(A.x); a1 += b2f_hi(A.x);
            a2 += b2f_lo(A.y); a3 += b2f_hi(A.y);
        }
    }
    for (; j < end; j += 2) {
        uint2 A = yr[(size_t)srcs[j] * 32 + u];
        a0 += b2f_lo(A.x); a1 += b2f_hi(A.x);
        a2 += b2f_lo(A.y); a3 += b2f_hi(A.y);
    }
    a0 += __shfl_xor(a0, 32, 64); a1 += __shfl_xor(a1, 32, 64);
    a2 += __shfl_xor(a2, 32, 64); a3 += __shfl_xor(a3, 32, 64);
    if (g == 0) {
        uint2 S = yr[(size_t)node * 32 + u];           // self row (bf16 y)
        float4 bv = ((const float4*)b1)[u];            // bias cols 4u..4u+3
        float f0 = fmaf(1.001f, b2f_lo(S.x), a0) + bv.x;
        float f1 = fmaf(1.001f, b2f_hi(S.x), a1) + bv.y;
        float f2 = fmaf(1.001f, b2f_lo(S.y), a2) + bv.z;
        float f3 = fmaf(1.001f, b2f_hi(S.y), a3) + bv.w;
        f0 = fmaxf(f0, 0.f); f1 = fmaxf(f1, 0.f);
        f2 = fmaxf(f2, 0.f); f3 = fmaxf(f3, 0.f);
        uint2 o;
        o.x = (unsigned)f2b(f0) | ((unsigned)f2b(f1) << 16);
        o.y = (unsigned)f2b(f2) | ((unsigned)f2b(f3) << 16);
        ((uint2*)h)[(size_t)node * 32 + u] = o;
    }
}

// ---------------- bf16 MFMA GEMM: out[M,128] = A_bf16[M,128] @ W[128,128] + b ---------
template <int RELU, int OUT_BF16>
__global__ __launch_bounds__(256, 2) void k_gemm(const unsigned short* __restrict__ A,
                                                 const float* __restrict__ Wg,
                                                 const float* __restrict__ bias,
                                                 void* __restrict__ outv, int M) {
    __shared__ short Al[128 * LPAD];   // [row][k]
    __shared__ short Wt[128 * LPAD];   // [n][k]  (transposed W)
    __shared__ float bl[128];

    int t = threadIdx.x;
    int row0 = blockIdx.x * 128;

    const uint4* A16 = (const uint4*)A;
    #pragma unroll
    for (int i = 0; i < 8; ++i) {
        int idx = i * 256 + t;      // 0..2047
        int r = idx >> 4;           // 0..127
        int c = idx & 15;           // uint4 within row
        uint4 v = make_uint4(0u, 0u, 0u, 0u);
        if (row0 + r < M) v = A16[(size_t)(row0 + r) * 16 + c];
        *(uint4*)&Al[r * LPAD + c * 8] = v;
    }
    const float4* W4 = (const float4*)Wg;
    #pragma unroll
    for (int i = 0; i < 16; ++i) {
        int idx = i * 256 + t;
        int k = idx >> 5;
        int n4 = idx & 31;
        float4 v = W4[k * 32 + n4];
        Wt[(n4 * 4 + 0) * LPAD + k] = (short)f2b(v.x);
        Wt[(n4 * 4 + 1) * LPAD + k] = (short)f2b(v.y);
        Wt[(n4 * 4 + 2) * LPAD + k] = (short)f2b(v.z);
        Wt[(n4 * 4 + 3) * LPAD + k] = (short)f2b(v.w);
    }
    if (t < 32) ((float4*)bl)[t] = ((const float4*)bias)[t];
    __syncthreads();

    int wave = t >> 6;
    int lane = t & 63;
    int quad = lane >> 4;
    int l16 = lane & 15;
    int rowbase = wave * 32;

    float4v acc[2][8];
    #pragma unroll
    for (int mt = 0; mt < 2; ++mt)
        #pragma unroll
        for (int nt = 0; nt < 8; ++nt)
            acc[mt][nt] = (float4v){0.f, 0.f, 0.f, 0.f};

    #pragma unroll
    for (int kc = 0; kc < 4; ++kc) {
        int koff = kc * 32 + quad * 8;
        short8 a0 = *(const short8*)&Al[(rowbase + l16) * LPAD + koff];
        short8 a1 = *(const short8*)&Al[(rowbase + 16 + l16) * LPAD + koff];
        #pragma unroll
        for (int nt = 0; nt < 8; ++nt) {
            short8 bfr = *(const short8*)&Wt[(nt * 16 + l16) * LPAD + koff];
            acc[0][nt] = __builtin_amdgcn_mfma_f32_16x16x32_bf16(a0, bfr, acc[0][nt], 0, 0, 0);
            acc[1][nt] = __builtin_amdgcn_mfma_f32_16x16x32_bf16(a1, bfr, acc[1][nt], 0, 0, 0);
        }
    }

    #pragma unroll
    for (int mt = 0; mt < 2; ++mt) {
        int rloc = rowbase + mt * 16 + quad * 4;
        #pragma unroll
        for (int nt = 0; nt < 8; ++nt) {
            int col = nt * 16 + l16;
            float bv = bl[col];
            #pragma unroll
            for (int r = 0; r < 4; ++r) {
                int grow = row0 + rloc + r;
                if (grow < M) {
                    float v = acc[mt][nt][r] + bv;
                    if (RELU) v = fmaxf(v, 0.f);
                    if (OUT_BF16)
                        ((unsigned short*)outv)[(size_t)grow * 128 + col] = f2b(v);
                    else
                        ((float*)outv)[(size_t)grow * 128 + col] = v;
                }
            }
        }
    }
}

extern "C" void kernel_launch(void* const* d_in, const int* in_sizes, int n_in,
                              void* d_out, int out_size, void* d_ws, size_t ws_size,
                              hipStream_t stream) {
    const float* x  = (const float*)d_in[0];
    const int*   ei = (const int*)d_in[1];
    const float* W1 = (const float*)d_in[2];
    const float* b1 = (const float*)d_in[3];
    const float* W2 = (const float*)d_in[4];
    const float* b2 = (const float*)d_in[5];
    float* out = (float*)d_out;

    // workspace layout (bytes):
    //   [0,        12.8e6)  y  bf16 (x @ W1)
    //   [12.8e6,   25.6e6)  h  bf16 (post-relu hidden)
    //   [25.6e6,   32.0e6)  pack u32: (rank<<16)|dst per edge
    //   [32.0e6,   38.4e6)  srcs (CSR-ordered source ids)
    //   [38.4e6,   41.6e6)  degp: 50000 x 16 u32 padded degree counters
    //   [41.6e6, ...)       offsets, bsum, flag
    char* ws = (char*)d_ws;
    unsigned short* y       = (unsigned short*)(ws);
    unsigned short* hb      = (unsigned short*)(ws + 12800000);
    unsigned*       pack    = (unsigned*)(ws + 25600000);
    int*            srcs    = (int*)  (ws + 32000000);
    unsigned*       degp    = (unsigned*)(ws + 38400000);
    int*            offsets = (int*)  (ws + 41600000);
    int*            bsum    = (int*)  (ws + 41800000);
    int*            flag    = (int*)  (ws + 41810000);

    const int NB_SCAN = (N_NODES + 511) / 512;  // 98
    int gblocks = (N_NODES + 127) / 128;        // 391

    k_gemmY<<<gblocks, 256, 0, stream>>>(x, W1, y, ei, flag, (uint4*)degp);
    k_count<<<(N_EDGES + 1023) / 1024, 1024, 0, stream>>>(ei, flag, degp, pack);
    k_scanA<<<NB_SCAN, 512, 0, stream>>>(degp, offsets, bsum);
    k_scan23<<<NB_SCAN, 512, 0, stream>>>(offsets, bsum, NB_SCAN);
    k_place<<<(N_EDGES + 1023) / 1024, 1024, 0, stream>>>(ei, flag, offsets, pack, srcs);
    k_gather<<<(N_NODES + 3) / 4, 256, 0, stream>>>(y, srcs, offsets, degp, b1, hb);
    k_gemm<0, 0><<<gblocks, 256, 0, stream>>>(hb, W2, b2, out, N_NODES);
}